// Round 11
// baseline (191.769 us; speedup 1.0000x reference)
//
#include <hip/hip_runtime.h>
#include <hip/hip_fp16.h>

typedef __attribute__((ext_vector_type(8))) short short8;
typedef __attribute__((ext_vector_type(4))) float f32x4;
typedef unsigned short ushort_t;
typedef unsigned int uint_t;

#define B_SZ 32
#define T_SZ 4096
#define D_IN 256
#define H_SZ 256
#define M_SZ (B_SZ * T_SZ)  // 131072
#define CHUNK 64
#define NCHUNK (T_SZ / CHUNK)  // 64

__device__ __forceinline__ ushort_t f2bf(float f) {
  unsigned int u = __float_as_uint(f);
  unsigned int r = (u + 0x7FFFu + ((u >> 16) & 1u)) >> 16;
  return (ushort_t)r;
}

__device__ __forceinline__ float sigmoidf_(float xv) {
  float e = __expf(-fabsf(xv));
  float s = 1.0f / (1.0f + e);
  return xv >= 0.0f ? s : 1.0f - s;
}

__device__ __forceinline__ float unpack_lo(uint_t pk) {
  return __half2float(__ushort_as_half((ushort_t)(pk & 0xFFFFu)));
}
__device__ __forceinline__ float unpack_hi(uint_t pk) {
  return __half2float(__ushort_as_half((ushort_t)(pk >> 16)));
}

// ---------------------------------------------------------------------------
// Kernel 1 (unchanged): pack W'' (Wz,Wh interleaved by 16-col groups) into
// bf16, GRANULE-MAJOR per kstep: granule = c*512 + n.
// ---------------------------------------------------------------------------
__global__ void prep_w(const float* __restrict__ Wz, const float* __restrict__ Wh,
                       ushort_t* __restrict__ wsB) {
  int g = blockIdx.x * 256 + threadIdx.x;  // 16384 granules total
  if (g >= 8 * 2048) return;
  int ks = g >> 11;
  int r = g & 2047;
  int c = r >> 9;        // 0..3
  int n = r & 511;       // 0..511
  int h = (n >> 5) * 16 + (n & 15);
  const float* W = ((n >> 4) & 1) ? Wh : Wz;
  const float* src = W + (size_t)h * D_IN + ks * 32 + c * 8;
  ushort_t* dst = wsB + (size_t)g * 8;
#pragma unroll
  for (int j = 0; j < 8; ++j) dst[j] = f2bf(src[j]);
}

// ---------------------------------------------------------------------------
// Kernel 2: counted-vmcnt K-loop (T4) on the r10 dataflow.
// BM=64 x BN=512, BK=32, 8 ksteps, 8 waves, wave tile 64x64, acc[4][4].
// A: ALL x loads issued in prologue into pf[8] (pinned by a compiler memory
//    fence so they cannot sink); per-kstep A write-late is reg->LDS only.
// B: 3-buffer LDS rotation (buf = ks%3). Kstep ks issues B(ks+2) into buf
//    (ks+2)%3 (last read at kstep ks-1, protected by that kstep's barrier).
// Barrier per kstep: s_waitcnt vmcnt(4) lgkmcnt(0); s_barrier. vmcnt(4)
//    waits only B(ks+1) (oldest 4 of 8 outstanding) -> ~2 ksteps of latency
//    cover, loads stay in flight ACROSS barriers (never drained to 0 except
//    the ks=6 edge where B(8) doesn't exist). lgkmcnt(0) makes the A ds_write
//    visible. No barrier after the last kstep.
// LDS: B 3x32KB + A 2x4KB = 104KB -> 1 block/CU.
// Epilogue: r9 verbatim (gate math + packed av + fused chunk-affine reduce).
// ---------------------------------------------------------------------------
__global__ __launch_bounds__(512, 1) void gemm_av(
    const float* __restrict__ x, const ushort_t* __restrict__ wsB,
    const float* __restrict__ bz, const float* __restrict__ bh,
    uint_t* __restrict__ av, float2* cAV) {
  __shared__ __align__(16) unsigned char lds[106496];
  ushort_t* As = (ushort_t*)lds;                  // 2 x 4096 B  (2048 el/buf)
  ushort_t* Bs = (ushort_t*)(lds + 8192);         // 3 x 32768 B (16384 el/buf)

  const int tid = threadIdx.x;
  const int lane = tid & 63;
  const int wid = tid >> 6;         // 0..7 = N-group
  const int m0 = blockIdx.x * 64;

  // A-stage mapping (ALL 512 threads): granule g = tid>>1, half = tid&1.
  const int a_row = (tid >> 1) & 63;
  const int a_c = tid >> 7;        // 0..3
  const int a_half = tid & 1;
  const float* asrc = x + (size_t)(m0 + a_row) * D_IN + a_c * 8 + a_half * 4;

  // B staging helper: issue kstep ks' 4 gload_lds into buffer `buf`
  auto STAGE_B = [&](int ks, int buf) {
    const ushort_t* bsrc = wsB + (size_t)ks * 16384 + wid * 2048 + lane * 8;
    ushort_t* bdst = Bs + buf * 16384 + wid * 2048;
#pragma unroll
    for (int cc = 0; cc < 4; ++cc) {
      __builtin_amdgcn_global_load_lds(
          (const __attribute__((address_space(1))) void*)(bsrc + cc * 512),
          (__attribute__((address_space(3))) void*)(bdst + cc * 512), 16, 0, 0);
    }
  };

  // ---- prologue ----
  STAGE_B(0, 0);
  STAGE_B(1, 1);

  float4 pf[8];
#pragma unroll
  for (int ks = 0; ks < 8; ++ks) pf[ks] = *(const float4*)(asrc + ks * 32);
  asm volatile("" ::: "memory");  // pin: all pf loads issued HERE, cannot sink

  f32x4 acc[4][4];
#pragma unroll
  for (int rt = 0; rt < 4; ++rt)
#pragma unroll
    for (int ct = 0; ct < 4; ++ct) {
      f32x4 z4 = {0.f, 0.f, 0.f, 0.f};
      acc[rt][ct] = z4;
    }

  {
    uint2 w;
    w.x = (uint_t)f2bf(pf[0].x) | ((uint_t)f2bf(pf[0].y) << 16);
    w.y = (uint_t)f2bf(pf[0].z) | ((uint_t)f2bf(pf[0].w) << 16);
    *(uint2*)((char*)As + tid * 8) = w;
  }
  __syncthreads();  // full drain once: B0, B1, all pf complete

#pragma unroll
  for (int ks = 0; ks < 8; ++ks) {
    const int rbuf = ks % 3;        // B read buffer
    const int acur = ks & 1;        // A read buffer
    // 1. LDS -> register fragments (granule-major)
    short8 afr[4], bfr[4];
    {
      const int c = lane >> 4;
      const int r16 = lane & 15;
#pragma unroll
      for (int rt = 0; rt < 4; ++rt) {
        int row = rt * 16 + r16;
        afr[rt] = *(const short8*)(As + acur * 2048 + (c * 64 + row) * 8);
      }
#pragma unroll
      for (int ct = 0; ct < 4; ++ct) {
        int n = wid * 64 + ct * 16 + r16;
        bfr[ct] = *(const short8*)(Bs + rbuf * 16384 + (c * 512 + n) * 8);
      }
    }
    // 2. issue B(ks+2) into buf (ks+2)%3 (that buf's last read was ks-1)
    if (ks < 6) STAGE_B(ks + 2, (ks + 2) % 3);
    // 3. MFMAs
#pragma unroll
    for (int rt = 0; rt < 4; ++rt)
#pragma unroll
      for (int ct = 0; ct < 4; ++ct)
        acc[rt][ct] = __builtin_amdgcn_mfma_f32_16x16x32_bf16(
            afr[rt], bfr[ct], acc[rt][ct], 0, 0, 0);
    // 4. A write-late from resident pf (static index)
    if (ks < 7) {
      uint2 w;
      w.x = (uint_t)f2bf(pf[ks + 1].x) | ((uint_t)f2bf(pf[ks + 1].y) << 16);
      w.y = (uint_t)f2bf(pf[ks + 1].z) | ((uint_t)f2bf(pf[ks + 1].w) << 16);
      *(uint2*)((char*)As + (acur ^ 1) * 4096 + tid * 8) = w;
    }
    // 5. counted-vmcnt barrier: wait B(ks+1) only; keep B(ks+2) in flight
    if (ks < 7) {
      if (ks < 6) {
        asm volatile("s_waitcnt vmcnt(4) lgkmcnt(0)" ::: "memory");
      } else {
        asm volatile("s_waitcnt vmcnt(0) lgkmcnt(0)" ::: "memory");
      }
      __builtin_amdgcn_s_barrier();
      __builtin_amdgcn_sched_barrier(0);
    }
  }

  // ---- epilogue (r9 verbatim): gate math + av + fused chunk-affine reduce ----
  const int col16 = lane & 15;
  const int rgrp = lane >> 4;
#pragma unroll
  for (int i = 0; i < 2; ++i) {
    int hh = (wid * 2 + i) * 16 + col16;
    float bzv = bz[hh];
    float bhv = bh[hh];
    float CA = 1.0f, CV = 0.0f;   // running compose over rt windows
#pragma unroll
    for (int rt = 0; rt < 4; ++rt) {
      float A4 = 1.0f, V4 = 0.0f; // this thread's 4 rows (ascending j = time)
#pragma unroll
      for (int j = 0; j < 4; ++j) {
        int row = m0 + rt * 16 + rgrp * 4 + j;
        float kv = acc[rt][2 * i][j] + bzv;
        float pv = acc[rt][2 * i + 1][j] + bhv;
        float a = sigmoidf_(-kv);       // 1 - sigmoid(k)
        float z = 1.0f - a;             // sigmoid(k)
        float gg = (pv >= 0.0f) ? (pv + 0.5f) : sigmoidf_(pv);
        float vv = z * gg;
        uint_t pk = (uint_t)__half_as_ushort(__float2half_rn(a)) |
                    ((uint_t)__half_as_ushort(__float2half_rn(vv)) << 16);
        av[(size_t)row * H_SZ + hh] = pk;
        V4 = fmaf(a, V4, vv);
        A4 *= a;
      }
      // butterfly compose across rgrp (time order)
      float Ap = __shfl_xor(A4, 16);
      float Vp = __shfl_xor(V4, 16);
      float A8 = A4 * Ap;
      float V8 = (lane & 16) ? fmaf(A4, Vp, V4) : fmaf(Ap, V4, Vp);
      float Ap2 = __shfl_xor(A8, 32);
      float Vp2 = __shfl_xor(V8, 32);
      float A16 = A8 * Ap2;
      float V16 = (lane & 32) ? fmaf(A8, Vp2, V8) : fmaf(Ap2, V8, Vp2);
      // rt windows ascend in time
      CV = fmaf(A16, CV, V16);
      CA = CA * A16;
    }
    if (cAV != nullptr && lane < 16) {
      float2 r; r.x = CA; r.y = CV;
      cAV[(size_t)blockIdx.x * H_SZ + hh] = r;  // chunkIdx == blockIdx.x
    }
  }
}

// ---------------------------------------------------------------------------
// Phase 2 (unchanged): per (b,h) sequentially compose chunk summaries from
// g(h0), writing the INCOMING h for each chunk. 32 blocks x 256 thr.
// ---------------------------------------------------------------------------
__global__ __launch_bounds__(256) void chunk_carry(
    const float* __restrict__ h0, const float2* __restrict__ cAV,
    float* __restrict__ hb) {
  const int b = blockIdx.x;
  const int h = threadIdx.x;
  float v0 = h0[b * H_SZ + h];
  float hc = (v0 >= 0.0f) ? (v0 + 0.5f) : sigmoidf_(v0);

  const float2* p = cAV + (size_t)b * NCHUNK * H_SZ + h;
  float* o = hb + (size_t)b * NCHUNK * H_SZ + h;

  float2 buf[NCHUNK];
#pragma unroll
  for (int c = 0; c < NCHUNK; ++c) buf[c] = p[(size_t)c * H_SZ];

#pragma unroll
  for (int c = 0; c < NCHUNK; ++c) {
    o[(size_t)c * H_SZ] = hc;
    hc = fmaf(buf[c].x, hc, buf[c].y);
  }
}

// ---------------------------------------------------------------------------
// Phase 3 (unchanged): per (b, chunk): start from carry, re-scan av, write
// fp32 out. av may alias out (in-place fallback).
// ---------------------------------------------------------------------------
__global__ __launch_bounds__(256) void chunk_scan_out(
    const uint_t* av, const float* __restrict__ hb, float* out) {
  const int b = blockIdx.x >> 6;
  const int c = blockIdx.x & 63;
  const int h = threadIdx.x;

  float hc = hb[((size_t)b * NCHUNK + c) * H_SZ + h];
  const uint_t* p = av + ((size_t)b * T_SZ + c * CHUNK) * H_SZ + h;
  float* o = out + ((size_t)b * T_SZ + c * CHUNK) * H_SZ + h;

  uint_t buf[CHUNK];
#pragma unroll
  for (int s = 0; s < CHUNK; ++s) buf[s] = p[(size_t)s * H_SZ];

#pragma unroll
  for (int s = 0; s < CHUNK; ++s) {
    float a = unpack_lo(buf[s]);
    float v = unpack_hi(buf[s]);
    hc = fmaf(a, hc, v);
    o[(size_t)s * H_SZ] = hc;
  }
}

// Fallback (unchanged): fully-sequential scan.
__global__ __launch_bounds__(64) void scan_seq(const float* __restrict__ h0,
                                               const uint_t* av, float* out) {
  const int b = blockIdx.x >> 2;
  const int hg = blockIdx.x & 3;
  const int h = hg * 64 + threadIdx.x;

  float v0 = h0[b * H_SZ + h];
  float hc = (v0 >= 0.0f) ? (v0 + 0.5f) : sigmoidf_(v0);

  const uint_t* p = av + (size_t)b * T_SZ * H_SZ + h;
  float* o = out + (size_t)b * T_SZ * H_SZ + h;

  uint_t buf[32];
#pragma unroll
  for (int d = 0; d < 32; ++d) buf[d] = p[(size_t)d * H_SZ];

  for (int t0 = 0; t0 < T_SZ; t0 += 32) {
#pragma unroll
    for (int d = 0; d < 32; ++d) {
      int t = t0 + d;
      uint_t pk = buf[d];
      int tn = t + 32;
      if (tn < T_SZ) buf[d] = p[(size_t)tn * H_SZ];
      hc = fmaf(unpack_lo(pk), hc, unpack_hi(pk));
      o[(size_t)t * H_SZ] = hc;
    }
  }
}

extern "C" void kernel_launch(void* const* d_in, const int* in_sizes, int n_in,
                              void* d_out, int out_size, void* d_ws, size_t ws_size,
                              hipStream_t stream) {
  const float* x  = (const float*)d_in[0];
  const float* h0 = (const float*)d_in[1];
  const float* Wz = (const float*)d_in[2];
  const float* bz = (const float*)d_in[3];
  const float* Wh = (const float*)d_in[4];
  const float* bh = (const float*)d_in[5];
  float* out = (float*)d_out;

  // ws layout: [wsB 256K][cAV 4M][hb 2M][pad to 8M][av 134M if it fits]
  const size_t wsBBytes = 262144;
  const size_t cavBytes = (size_t)B_SZ * NCHUNK * H_SZ * 8;   // 4 MiB
  const size_t hbBytes  = (size_t)B_SZ * NCHUNK * H_SZ * 4;   // 2 MiB
  const size_t avOff    = 8388608;
  const size_t avBytes  = (size_t)M_SZ * H_SZ * 4;            // 134 MiB

  ushort_t* wsB = (ushort_t*)d_ws;
  float2* cAV = (float2*)((char*)d_ws + wsBBytes);
  float* hb   = (float*)((char*)d_ws + wsBBytes + cavBytes);

  const bool haveSummaries = ws_size >= wsBBytes + cavBytes + hbBytes;
  uint_t* av;
  if (ws_size >= avOff + avBytes) {
    av = (uint_t*)((char*)d_ws + avOff);
  } else {
    av = (uint_t*)d_out;  // in-place: scan reads av[t] before writing h[t]
  }

  prep_w<<<64, 256, 0, stream>>>(Wz, Wh, wsB);
  gemm_av<<<M_SZ / 64, 512, 0, stream>>>(x, wsB, bz, bh, av,
                                         haveSummaries ? cAV : (float2*)nullptr);
  if (haveSummaries) {
    chunk_carry<<<B_SZ, 256, 0, stream>>>(h0, cAV, hb);
    chunk_scan_out<<<B_SZ * NCHUNK, 256, 0, stream>>>(av, hb, out);
  } else {
    scan_seq<<<B_SZ * 4, 64, 0, stream>>>(h0, av, out);
  }
}

// Round 12
// 182.875 us; speedup vs baseline: 1.0486x; 1.0486x over previous
//
#include <hip/hip_runtime.h>
#include <hip/hip_fp16.h>

typedef __attribute__((ext_vector_type(8))) short short8;
typedef __attribute__((ext_vector_type(4))) float f32x4;
typedef unsigned short ushort_t;
typedef unsigned int uint_t;

#define B_SZ 32
#define T_SZ 4096
#define D_IN 256
#define H_SZ 256
#define M_SZ (B_SZ * T_SZ)  // 131072
#define CHUNK 64
#define NCHUNK (T_SZ / CHUNK)  // 64

__device__ __forceinline__ ushort_t f2bf(float f) {
  unsigned int u = __float_as_uint(f);
  unsigned int r = (u + 0x7FFFu + ((u >> 16) & 1u)) >> 16;
  return (ushort_t)r;
}

__device__ __forceinline__ float sigmoidf_(float xv) {
  float e = __expf(-fabsf(xv));
  float s = 1.0f / (1.0f + e);
  return xv >= 0.0f ? s : 1.0f - s;
}

__device__ __forceinline__ float unpack_lo(uint_t pk) {
  return __half2float(__ushort_as_half((ushort_t)(pk & 0xFFFFu)));
}
__device__ __forceinline__ float unpack_hi(uint_t pk) {
  return __half2float(__ushort_as_half((ushort_t)(pk >> 16)));
}

// ---------------------------------------------------------------------------
// Kernel 1 (unchanged): pack W'' (Wz,Wh interleaved by 16-col groups) into
// bf16, GRANULE-MAJOR per kstep: source granule g = ks*2048 + c*512 + n.
// W''[n] -> gate = (n>>4)&1 (0=Wz,1=Wh), h = (n>>5)*16 + (n&15).
// ---------------------------------------------------------------------------
__global__ void prep_w(const float* __restrict__ Wz, const float* __restrict__ Wh,
                       ushort_t* __restrict__ wsB) {
  int g = blockIdx.x * 256 + threadIdx.x;  // 16384 granules total
  if (g >= 8 * 2048) return;
  int ks = g >> 11;
  int r = g & 2047;
  int c = r >> 9;        // 0..3
  int n = r & 511;       // 0..511
  int h = (n >> 5) * 16 + (n & 15);
  const float* W = ((n >> 4) & 1) ? Wh : Wz;
  const float* src = W + (size_t)h * D_IN + ks * 32 + c * 8;
  ushort_t* dst = wsB + (size_t)g * 8;
#pragma unroll
  for (int j = 0; j < 8; ++j) dst[j] = f2bf(src[j]);
}

// ---------------------------------------------------------------------------
// Kernel 2: occupancy-first GEMM. BM=64 x BN=256 (half the interleaved cols),
// BK=32, 8 ksteps. 256 threads = 4 waves, wave tile 64x64, acc[4][4].
// Grid = 2048 chunks x 2 n-halves; bid = chunk*2 + nhalf.
// LDS = A 2x4KB + B 2x16KB = 40KB -> 4 blocks/CU (vs r3's 2): four
// independent barrier groups per CU overlap each other's staging drains.
// A: thread t stages granule t (row=t&63, c=t>>6): 2 float4 loads ->
//    8x f2bf -> one short8 LDS write (T14 load-early/write-late).
// B: global_load_lds width=16; staging wave wid covers k-chunk c=wid,
//    call cc covers nn = cc*64+lane: src granule = ks*2048 + wid*512 +
//    n0 + cc*64 + lane, dest granule (in-buffer) = wid*256 + cc*64 + lane.
// Read granule (in-buffer) = c*256 + nn, nn = wid*64 + ct*16 + r16.
// Epilogue: gate math + packed av + fused chunk-affine reduce (r9 pattern);
// hh = nhalf*128 + (wid*2+i)*16 + col16; cAV chunk = bid>>1.
// ---------------------------------------------------------------------------
__global__ __launch_bounds__(256, 4) void gemm_av(
    const float* __restrict__ x, const ushort_t* __restrict__ wsB,
    const float* __restrict__ bz, const float* __restrict__ bh,
    uint_t* __restrict__ av, float2* cAV) {
  __shared__ __align__(16) unsigned char lds[40960];
  ushort_t* As = (ushort_t*)lds;                  // 2 x 4096 B  (2048 el/buf)
  ushort_t* Bs = (ushort_t*)(lds + 8192);         // 2 x 16384 B (8192 el/buf)

  const int tid = threadIdx.x;
  const int lane = tid & 63;
  const int wid = tid >> 6;         // 0..3 = N-group (and staging k-chunk)
  const int bid = blockIdx.x;
  const int m0 = (bid >> 1) * 64;
  const int n0 = (bid & 1) * 256;   // interleaved-col base

  // A-stage mapping: thread t owns granule t: row = t&63, c = t>>6.
  const int a_row = tid & 63;
  const int a_c = tid >> 6;
  const float* asrc = x + (size_t)(m0 + a_row) * D_IN + a_c * 8;

  // B staging: issue kstep ks into buffer buf (4 calls x 1KB per wave)
  auto STAGE_B = [&](int ks, int buf) {
    const ushort_t* bsrc = wsB + ((size_t)ks * 2048 + wid * 512 + n0) * 8 + lane * 8;
    ushort_t* bdst = Bs + buf * 8192 + (wid * 256) * 8;
#pragma unroll
    for (int cc = 0; cc < 4; ++cc) {
      __builtin_amdgcn_global_load_lds(
          (const __attribute__((address_space(1))) void*)(bsrc + cc * 512),
          (__attribute__((address_space(3))) void*)(bdst + cc * 512), 16, 0, 0);
    }
  };

  f32x4 acc[4][4];
#pragma unroll
  for (int rt = 0; rt < 4; ++rt)
#pragma unroll
    for (int ct = 0; ct < 4; ++ct) {
      f32x4 z4 = {0.f, 0.f, 0.f, 0.f};
      acc[rt][ct] = z4;
    }

  // ---- prologue: stage kstep 0 into buffer 0 ----
  STAGE_B(0, 0);
  {
    float4 f0 = *(const float4*)(asrc);
    float4 f1 = *(const float4*)(asrc + 4);
    union { ushort_t e[8]; short8 s; } cv;
    cv.e[0] = f2bf(f0.x); cv.e[1] = f2bf(f0.y);
    cv.e[2] = f2bf(f0.z); cv.e[3] = f2bf(f0.w);
    cv.e[4] = f2bf(f1.x); cv.e[5] = f2bf(f1.y);
    cv.e[6] = f2bf(f1.z); cv.e[7] = f2bf(f1.w);
    *(short8*)(As + tid * 8) = cv.s;
  }
  __syncthreads();

#pragma unroll
  for (int ks = 0; ks < 8; ++ks) {
    const int cur = ks & 1;
    // 1. LDS -> register fragments
    short8 afr[4], bfr[4];
    {
      const int c = lane >> 4;
      const int r16 = lane & 15;
#pragma unroll
      for (int rt = 0; rt < 4; ++rt) {
        int row = rt * 16 + r16;
        afr[rt] = *(const short8*)(As + cur * 2048 + (c * 64 + row) * 8);
      }
#pragma unroll
      for (int ct = 0; ct < 4; ++ct) {
        int nn = wid * 64 + ct * 16 + r16;
        bfr[ct] = *(const short8*)(Bs + cur * 8192 + (c * 256 + nn) * 8);
      }
    }
    // 2. issue next-kstep staging (latency hides under MFMAs)
    float4 nf0, nf1;
    if (ks < 7) {
      STAGE_B(ks + 1, cur ^ 1);
      nf0 = *(const float4*)(asrc + (ks + 1) * 32);
      nf1 = *(const float4*)(asrc + (ks + 1) * 32 + 4);
    }
    // 3. MFMAs
#pragma unroll
    for (int rt = 0; rt < 4; ++rt)
#pragma unroll
      for (int ct = 0; ct < 4; ++ct)
        acc[rt][ct] = __builtin_amdgcn_mfma_f32_16x16x32_bf16(
            afr[rt], bfr[ct], acc[rt][ct], 0, 0, 0);
    // 4. A write-late (reg->LDS after compute)
    if (ks < 7) {
      union { ushort_t e[8]; short8 s; } cv;
      cv.e[0] = f2bf(nf0.x); cv.e[1] = f2bf(nf0.y);
      cv.e[2] = f2bf(nf0.z); cv.e[3] = f2bf(nf0.w);
      cv.e[4] = f2bf(nf1.x); cv.e[5] = f2bf(nf1.y);
      cv.e[6] = f2bf(nf1.z); cv.e[7] = f2bf(nf1.w);
      *(short8*)(As + (cur ^ 1) * 2048 + tid * 8) = cv.s;
    }
    __syncthreads();
  }

  // ---- epilogue: gate math + av + fused chunk-affine reduce ----
  const int col16 = lane & 15;
  const int rgrp = lane >> 4;
#pragma unroll
  for (int i = 0; i < 2; ++i) {
    int hh = (bid & 1) * 128 + (wid * 2 + i) * 16 + col16;
    float bzv = bz[hh];
    float bhv = bh[hh];
    float CA = 1.0f, CV = 0.0f;   // running compose over rt windows
#pragma unroll
    for (int rt = 0; rt < 4; ++rt) {
      float A4 = 1.0f, V4 = 0.0f; // this thread's 4 rows (ascending j = time)
#pragma unroll
      for (int j = 0; j < 4; ++j) {
        int row = m0 + rt * 16 + rgrp * 4 + j;
        float kv = acc[rt][2 * i][j] + bzv;
        float pv = acc[rt][2 * i + 1][j] + bhv;
        float a = sigmoidf_(-kv);       // 1 - sigmoid(k)
        float z = 1.0f - a;             // sigmoid(k)
        float gg = (pv >= 0.0f) ? (pv + 0.5f) : sigmoidf_(pv);
        float vv = z * gg;
        uint_t pk = (uint_t)__half_as_ushort(__float2half_rn(a)) |
                    ((uint_t)__half_as_ushort(__float2half_rn(vv)) << 16);
        av[(size_t)row * H_SZ + hh] = pk;
        V4 = fmaf(a, V4, vv);
        A4 *= a;
      }
      // butterfly compose across rgrp (time order)
      float Ap = __shfl_xor(A4, 16);
      float Vp = __shfl_xor(V4, 16);
      float A8 = A4 * Ap;
      float V8 = (lane & 16) ? fmaf(A4, Vp, V4) : fmaf(Ap, V4, Vp);
      float Ap2 = __shfl_xor(A8, 32);
      float Vp2 = __shfl_xor(V8, 32);
      float A16 = A8 * Ap2;
      float V16 = (lane & 32) ? fmaf(A8, Vp2, V8) : fmaf(Ap2, V8, Vp2);
      // rt windows ascend in time
      CV = fmaf(A16, CV, V16);
      CA = CA * A16;
    }
    if (cAV != nullptr && lane < 16) {
      float2 r; r.x = CA; r.y = CV;
      cAV[(size_t)(bid >> 1) * H_SZ + hh] = r;  // chunkIdx == bid>>1
    }
  }
}

// ---------------------------------------------------------------------------
// Phase 2 (unchanged): per (b,h) sequentially compose chunk summaries from
// g(h0), writing the INCOMING h for each chunk. 32 blocks x 256 thr.
// ---------------------------------------------------------------------------
__global__ __launch_bounds__(256) void chunk_carry(
    const float* __restrict__ h0, const float2* __restrict__ cAV,
    float* __restrict__ hb) {
  const int b = blockIdx.x;
  const int h = threadIdx.x;
  float v0 = h0[b * H_SZ + h];
  float hc = (v0 >= 0.0f) ? (v0 + 0.5f) : sigmoidf_(v0);

  const float2* p = cAV + (size_t)b * NCHUNK * H_SZ + h;
  float* o = hb + (size_t)b * NCHUNK * H_SZ + h;

  float2 buf[NCHUNK];
#pragma unroll
  for (int c = 0; c < NCHUNK; ++c) buf[c] = p[(size_t)c * H_SZ];

#pragma unroll
  for (int c = 0; c < NCHUNK; ++c) {
    o[(size_t)c * H_SZ] = hc;
    hc = fmaf(buf[c].x, hc, buf[c].y);
  }
}

// ---------------------------------------------------------------------------
// Phase 3 (unchanged): per (b, chunk): start from carry, re-scan av, write
// fp32 out. av may alias out (in-place fallback).
// ---------------------------------------------------------------------------
__global__ __launch_bounds__(256) void chunk_scan_out(
    const uint_t* av, const float* __restrict__ hb, float* out) {
  const int b = blockIdx.x >> 6;
  const int c = blockIdx.x & 63;
  const int h = threadIdx.x;

  float hc = hb[((size_t)b * NCHUNK + c) * H_SZ + h];
  const uint_t* p = av + ((size_t)b * T_SZ + c * CHUNK) * H_SZ + h;
  float* o = out + ((size_t)b * T_SZ + c * CHUNK) * H_SZ + h;

  uint_t buf[CHUNK];
#pragma unroll
  for (int s = 0; s < CHUNK; ++s) buf[s] = p[(size_t)s * H_SZ];

#pragma unroll
  for (int s = 0; s < CHUNK; ++s) {
    float a = unpack_lo(buf[s]);
    float v = unpack_hi(buf[s]);
    hc = fmaf(a, hc, v);
    o[(size_t)s * H_SZ] = hc;
  }
}

// Fallback (unchanged): fully-sequential scan.
__global__ __launch_bounds__(64) void scan_seq(const float* __restrict__ h0,
                                               const uint_t* av, float* out) {
  const int b = blockIdx.x >> 2;
  const int hg = blockIdx.x & 3;
  const int h = hg * 64 + threadIdx.x;

  float v0 = h0[b * H_SZ + h];
  float hc = (v0 >= 0.0f) ? (v0 + 0.5f) : sigmoidf_(v0);

  const uint_t* p = av + (size_t)b * T_SZ * H_SZ + h;
  float* o = out + (size_t)b * T_SZ * H_SZ + h;

  uint_t buf[32];
#pragma unroll
  for (int d = 0; d < 32; ++d) buf[d] = p[(size_t)d * H_SZ];

  for (int t0 = 0; t0 < T_SZ; t0 += 32) {
#pragma unroll
    for (int d = 0; d < 32; ++d) {
      int t = t0 + d;
      uint_t pk = buf[d];
      int tn = t + 32;
      if (tn < T_SZ) buf[d] = p[(size_t)tn * H_SZ];
      hc = fmaf(unpack_lo(pk), hc, unpack_hi(pk));
      o[(size_t)t * H_SZ] = hc;
    }
  }
}

extern "C" void kernel_launch(void* const* d_in, const int* in_sizes, int n_in,
                              void* d_out, int out_size, void* d_ws, size_t ws_size,
                              hipStream_t stream) {
  const float* x  = (const float*)d_in[0];
  const float* h0 = (const float*)d_in[1];
  const float* Wz = (const float*)d_in[2];
  const float* bz = (const float*)d_in[3];
  const float* Wh = (const float*)d_in[4];
  const float* bh = (const float*)d_in[5];
  float* out = (float*)d_out;

  // ws layout: [wsB 256K][cAV 4M][hb 2M][pad to 8M][av 134M if it fits]
  const size_t wsBBytes = 262144;
  const size_t cavBytes = (size_t)B_SZ * NCHUNK * H_SZ * 8;   // 4 MiB
  const size_t hbBytes  = (size_t)B_SZ * NCHUNK * H_SZ * 4;   // 2 MiB
  const size_t avOff    = 8388608;
  const size_t avBytes  = (size_t)M_SZ * H_SZ * 4;            // 134 MiB

  ushort_t* wsB = (ushort_t*)d_ws;
  float2* cAV = (float2*)((char*)d_ws + wsBBytes);
  float* hb   = (float*)((char*)d_ws + wsBBytes + cavBytes);

  const bool haveSummaries = ws_size >= wsBBytes + cavBytes + hbBytes;
  uint_t* av;
  if (ws_size >= avOff + avBytes) {
    av = (uint_t*)((char*)d_ws + avOff);
  } else {
    av = (uint_t*)d_out;  // in-place: scan reads av[t] before writing h[t]
  }

  prep_w<<<64, 256, 0, stream>>>(Wz, Wh, wsB);
  gemm_av<<<(M_SZ / 64) * 2, 256, 0, stream>>>(x, wsB, bz, bh, av,
                                               haveSummaries ? cAV : (float2*)nullptr);
  if (haveSummaries) {
    chunk_carry<<<B_SZ, 256, 0, stream>>>(h0, cAV, hb);
    chunk_scan_out<<<B_SZ * NCHUNK, 256, 0, stream>>>(av, hb, out);
  } else {
    scan_seq<<<B_SZ * 4, 64, 0, stream>>>(h0, av, out);
  }
}